// Round 14
// baseline (101.668 us; speedup 1.0000x reference)
//
#include <hip/hip_runtime.h>
#include <math.h>

// CapsuleLayer dynamic routing, fully fused: one block per batch element.
// B=256, O=10, U=36, S=32, E=16, F=8, N=1152, 3 routing iterations.
//
// u_hat is never materialized:
//   v_pre[o,e]  = sum_{u,f} W[o,u,e,f] * cx[o,u,f],  cx[o,u,f] = sum_s c[o,n]*x[n,f]
//   b[o,n]     += sum_f x[n,f] * wv[o,u,f],          wv[o,u,f] = sum_e W[o,u,e,f]*v[o,e]
//
// Round-14 = round-13 (passing, 46.5us) + MLP-only changes (no structural or
// arithmetic edits — two recent rounds lost to bugs):
//  - v_pre: FULL unroll of the 12-u loop -> all 24 W b128 loads issue before
//    the FMA chain: one ~200cy L2 exposure per phase instead of three.
//  - cx: unroll 4 -> 8 (more LDS reads in flight on the 32-step chain).
//  - wv: j-loop manually unrolled (j=jp, jp+2, cond jp+4) so both/all u's
//    16-load groups overlap.
//
// Schedule (r11): only the v-reduction is block-wide; wv/bsm/softmax/cx are
// WAVE-LOCAL (each u's 32 rows live in one half-wave, so the c a wave's cx
// needs is produced by that wave's own bsm). 2 block barriers/iter.
// WAVESYNC (r13, rule #18): sched_barrier(0) + s_waitcnt lgkmcnt(0) +
// sched_barrier(0) — wave_barrier alone lets hipcc hoist LDS ops across.
// Bank fixes (r12): s_c o-pitch 1153 (mod32=1), s_vp o-stride 49 (mod32=17),
// wv roles o=l/4 (quad lanes share o -> broadcast SUMVP), cx roles o=l/nu.
// 512 threads = 8 waves; rows: n=t (u 0..15), n=512+t (u 16..31), rows
// 1024..1151 on waves 2..5 lanes 0..31 -> wave u-counts {4,4,5,5,5,5,4,4}.
//
// LDS swizzles (r5/r7): u-stride is 32 rows -> 32*pitch = 0 mod 32 banks for
// any pitch, so rotate slots by u:
//   x row (u,s), 16B half h' -> word u*256 + ((2s + h' + u)&63)*4
//   c[o][n]                  -> word o*1153 + u*32 + ((s+u)&31)

namespace {

constexpr int kO = 10;
constexpr int kU = 36;
constexpr int kS = 32;
constexpr int kE = 16;
constexpr int kF = 8;
constexpr int kN = kU * kS;   // 1152
constexpr int kIters = 3;
constexpr int kThreads = 512; // 8 waves, 2 per SIMD
constexpr int kPitch = 12;    // padded (o,u)-row pitch for s_cx/s_wv
constexpr int kCP = 1153;     // s_c o-pitch (mod 32 = 1: conflict-free o-spread)
constexpr int kVP = 49;       // s_vp o-stride (mod 32 = 17)

// wave-internal LDS ordering fence (rule #18: sched_barrier pins scheduling;
// same-wave DS ops drain with lgkmcnt(0))
#define WAVESYNC()                                              \
  do {                                                          \
    __builtin_amdgcn_sched_barrier(0);                          \
    asm volatile("s_waitcnt lgkmcnt(0)" ::: "memory");          \
    __builtin_amdgcn_sched_barrier(0);                          \
  } while (0)

__launch_bounds__(kThreads, 2)
__global__ void caps_routing_kernel(const float* __restrict__ xg,
                                    const float* __restrict__ Wg,
                                    float* __restrict__ outg) {
  __shared__ float s_x[kN * kF];            // 36.9 KB, swizzled
  __shared__ float s_c[kO * kCP];           // 46.1 KB, swizzled + o-padded
  __shared__ float s_cx[kO * kU * kPitch];  // 17.3 KB
  __shared__ float s_wv[kO * kU * kPitch];  // 17.3 KB
  __shared__ float s_vp[kO * kVP];          //  2.0 KB (o-padded)
  __shared__ float s_sx[kU * kF];           //  1.2 KB (sum_s x, for it=0)
  // total ~118 KB -> 1 block/CU

  const int t = threadIdx.x;
  const int w = t >> 6;
  const int l = t & 63;
  const int b = blockIdx.x;

  const bool five = (w >= 2 && w < 6);   // waves owning a u in 32..35
  const int nu = five ? 5 : 4;           // u's owned by this wave
  const bool has3 = five && (l < 32);    // lanes holding a third row

  // row geometry
  const int u0r = t >> 5;                // rows 0..511    -> u 0..15
  const int s0r = t & 31;
  const int rot0 = (s0r + u0r) & 31;
  const int u1r = 16 + (t >> 5);         // rows 512..1023 -> u 16..31
  const int rot1 = (s0r + u1r) & 31;
  const int u2r = 30 + w;                // rows 1024..1151 -> u 32..35 (w 2..5)
  const int rot2 = (l + u2r) & 31;

  float xr0[kF], xr1[kF], xr2[kF];
  float br0[kO], br1[kO], br2[kO];

  // ---- prologue: load rows -> regs + swizzled LDS; half-wave butterfly sx ----
#define STAGEROW(XR, N, U, S)                                                 \
  {                                                                           \
    const float4* src_ =                                                      \
        reinterpret_cast<const float4*>(xg + ((size_t)b * kN + (N)) * kF);    \
    const float4 a0_ = src_[0];                                               \
    const float4 a1_ = src_[1];                                               \
    XR[0] = a0_.x; XR[1] = a0_.y; XR[2] = a0_.z; XR[3] = a0_.w;               \
    XR[4] = a1_.x; XR[5] = a1_.y; XR[6] = a1_.z; XR[7] = a1_.w;               \
    const int sl0_ = (((S) << 1) + (U)) & 63;                                 \
    const int sl1_ = (((S) << 1) + 1 + (U)) & 63;                             \
    *reinterpret_cast<float4*>(&s_x[(U) * 256 + sl0_ * 4]) = a0_;             \
    *reinterpret_cast<float4*>(&s_x[(U) * 256 + sl1_ * 4]) = a1_;             \
    float4 r0_ = a0_, r1_ = a1_;                                              \
    _Pragma("unroll")                                                         \
    for (int m_ = 1; m_ <= 16; m_ <<= 1) {                                    \
      r0_.x += __shfl_xor(r0_.x, m_); r0_.y += __shfl_xor(r0_.y, m_);         \
      r0_.z += __shfl_xor(r0_.z, m_); r0_.w += __shfl_xor(r0_.w, m_);         \
      r1_.x += __shfl_xor(r1_.x, m_); r1_.y += __shfl_xor(r1_.y, m_);         \
      r1_.z += __shfl_xor(r1_.z, m_); r1_.w += __shfl_xor(r1_.w, m_);         \
    }                                                                         \
    if ((S) == 0) {                                                           \
      *reinterpret_cast<float4*>(&s_sx[(U) * kF + 0]) = r0_;                  \
      *reinterpret_cast<float4*>(&s_sx[(U) * kF + 4]) = r1_;                  \
    }                                                                         \
  }

  STAGEROW(xr0, t, u0r, s0r)
  STAGEROW(xr1, t + 512, u1r, s0r)
  if (has3) STAGEROW(xr2, 1024 + (w - 2) * 32 + l, u2r, l)
#undef STAGEROW
#pragma unroll
  for (int o = 0; o < kO; ++o) { br0[o] = 0.f; br1[o] = 0.f; br2[o] = 0.f; }
  __syncthreads();

  // wave's j-th owned u (j in 0..nu-1)
#define UOFJ(J) ((J) < 2 ? 2 * w + (J) : ((J) < 4 ? 14 + 2 * w + (J) : 30 + w))

  for (int it = 0; it <= kIters; ++it) {
    // ---- v_pre partials (block-wide): thread=(o,e,uc), 480 active ----
    // FULL unroll: all 24 W b128 loads issue before the FMA chain (one L2
    // latency exposure instead of three at unroll-4).
    if (l < 60) {
      const int i = w * 60 + l;  // 0..479
      const int o = i / 48;
      const int r = i - o * 48;
      const int e = r / 3;
      const int uc = r - e * 3;
      const int u0 = uc * 12;
      float accA = 0.f, accB = 0.f;
      const float* wrow = Wg + ((size_t)(o * kU + u0) * kE + e) * kF;
      if (it == 0) {
#pragma unroll
        for (int ui = 0; ui < 12; ++ui) {
          const float4* wp = reinterpret_cast<const float4*>(wrow);
          const float4 w0 = wp[0];
          const float4 w1 = wp[1];
          const float4* cp =
              reinterpret_cast<const float4*>(&s_sx[(u0 + ui) * kF]);
          const float4 c0 = cp[0];
          const float4 c1 = cp[1];
          accA += w0.x * c0.x + w0.y * c0.y + w0.z * c0.z + w0.w * c0.w;
          accB += w1.x * c1.x + w1.y * c1.y + w1.z * c1.z + w1.w * c1.w;
          wrow += kE * kF;
        }
        accA = (accA + accB) * 0.1f;
      } else {
#pragma unroll
        for (int ui = 0; ui < 12; ++ui) {
          const float4* wp = reinterpret_cast<const float4*>(wrow);
          const float4 w0 = wp[0];
          const float4 w1 = wp[1];
          const float4* cp = reinterpret_cast<const float4*>(
              &s_cx[(o * kU + u0 + ui) * kPitch]);
          const float4 c0 = cp[0];
          const float4 c1 = cp[1];
          accA += w0.x * c0.x + w0.y * c0.y + w0.z * c0.z + w0.w * c0.w;
          accB += w1.x * c1.x + w1.y * c1.y + w1.z * c1.z + w1.w * c1.w;
          wrow += kE * kF;
        }
        accA += accB;
      }
      s_vp[o * kVP + e * 3 + uc] = accA;
    }
    __syncthreads();

    // ---- final pass: squash + store output, done ----
    if (it == kIters) {
      if (t < kO * kE) {
        const int o = t >> 4;
        const int e = t & 15;
        const float vsum = s_vp[o * kVP + e * 3 + 0] +
                           s_vp[o * kVP + e * 3 + 1] +
                           s_vp[o * kVP + e * 3 + 2];
        float n2 = vsum * vsum;
#pragma unroll
        for (int m = 1; m <= 8; m <<= 1) n2 += __shfl_xor(n2, m);
        const float scale = sqrtf(n2) / (1.f + n2);
        outg[(size_t)b * kO * kE + t] = vsum * scale;
      }
      break;
    }

    // ================= wave-local interval: wv -> bsm -> cx =================

    // (a) wv for this wave's u's: roles l<40: o=l/4 (slow), q=l%4 -> fh,jp.
    // Quad lanes share o -> SUMVP reads broadcast; o-stride 49 mod32=17.
    // j-loop manually unrolled so both u's load groups overlap.
    if (l < 40) {
      const int o = l >> 2;
      const int q = l & 3;
      const int fh = q & 1;
      const int jp = q >> 1;
      // rebuild v[o,:] + squash scale from s_vp (broadcast reads)
#define SUMVP(E_) (s_vp[o * kVP + (E_) * 3 + 0] + \
                   s_vp[o * kVP + (E_) * 3 + 1] + \
                   s_vp[o * kVP + (E_) * 3 + 2])
      float4 va, vb, vc, vd;
      va.x = SUMVP(0);  va.y = SUMVP(1);  va.z = SUMVP(2);  va.w = SUMVP(3);
      vb.x = SUMVP(4);  vb.y = SUMVP(5);  vb.z = SUMVP(6);  vb.w = SUMVP(7);
      vc.x = SUMVP(8);  vc.y = SUMVP(9);  vc.z = SUMVP(10); vc.w = SUMVP(11);
      vd.x = SUMVP(12); vd.y = SUMVP(13); vd.z = SUMVP(14); vd.w = SUMVP(15);
#undef SUMVP
      const float n2 =
          va.x * va.x + va.y * va.y + va.z * va.z + va.w * va.w +
          vb.x * vb.x + vb.y * vb.y + vb.z * vb.z + vb.w * vb.w +
          vc.x * vc.x + vc.y * vc.y + vc.z * vc.z + vc.w * vc.w +
          vd.x * vd.x + vd.y * vd.y + vd.z * vd.z + vd.w * vd.w;
      const float scale = sqrtf(n2) / (1.f + n2);
      va.x *= scale; va.y *= scale; va.z *= scale; va.w *= scale;
      vb.x *= scale; vb.y *= scale; vb.z *= scale; vb.w *= scale;
      vc.x *= scale; vc.y *= scale; vc.z *= scale; vc.w *= scale;
      vd.x *= scale; vd.y *= scale; vd.z *= scale; vd.w *= scale;
#define WVU(J)                                                                \
  {                                                                           \
    const int u_ = UOFJ(J);                                                   \
    const float* wbase_ = Wg + (size_t)((o * kU + u_) * kE) * kF + fh * 4;    \
    float4 acc_ = make_float4(0.f, 0.f, 0.f, 0.f);                            \
    _Pragma("unroll")                                                         \
    for (int e_ = 0; e_ < kE; ++e_) {                                         \
      const float4 w4_ =                                                      \
          *reinterpret_cast<const float4*>(wbase_ + e_ * kF);                 \
      const float ve_ =                                                       \
          (e_ < 4 ? (&va.x)[e_] : e_ < 8 ? (&vb.x)[e_ - 4]                    \
           : e_ < 12 ? (&vc.x)[e_ - 8] : (&vd.x)[e_ - 12]);                   \
      acc_.x += ve_ * w4_.x; acc_.y += ve_ * w4_.y;                           \
      acc_.z += ve_ * w4_.z; acc_.w += ve_ * w4_.w;                           \
    }                                                                         \
    *reinterpret_cast<float4*>(&s_wv[(o * kU + u_) * kPitch + fh * 4]) = acc_;\
  }
      WVU(jp)
      WVU(jp + 2)
      if (jp + 4 < nu) WVU(4)  // only jp==0 reaches here (nu==5)
#undef WVU
    }
    WAVESYNC();  // wv (own wave) visible to bsm (own wave)

    // (b) bsm: b[o,n] += x.wv; thread-local softmax over o; write c to s_c
#define BSMROW(XR, BR, U, ROT)                                                \
  {                                                                           \
    float mx_ = -3.4e38f;                                                     \
    _Pragma("unroll")                                                         \
    for (int o_ = 0; o_ < kO; ++o_) {                                         \
      const float4* wp_ =                                                     \
          reinterpret_cast<const float4*>(&s_wv[(o_ * kU + (U)) * kPitch]);   \
      const float4 w0_ = wp_[0];                                              \
      const float4 w1_ = wp_[1];                                              \
      BR[o_] += w0_.x * XR[0] + w0_.y * XR[1] + w0_.z * XR[2] + w0_.w * XR[3] \
              + w1_.x * XR[4] + w1_.y * XR[5] + w1_.z * XR[6] + w1_.w * XR[7];\
      mx_ = fmaxf(mx_, BR[o_]);                                               \
    }                                                                         \
    float ex_[kO];                                                            \
    float sum_ = 0.f;                                                         \
    _Pragma("unroll")                                                         \
    for (int o_ = 0; o_ < kO; ++o_) {                                         \
      ex_[o_] = __expf(BR[o_] - mx_);                                         \
      sum_ += ex_[o_];                                                        \
    }                                                                         \
    const float inv_ = 1.f / sum_;                                            \
    _Pragma("unroll")                                                         \
    for (int o_ = 0; o_ < kO; ++o_)                                           \
      s_c[o_ * kCP + (U) * 32 + (ROT)] = ex_[o_] * inv_;                      \
  }
    BSMROW(xr0, br0, u0r, rot0)
    BSMROW(xr1, br1, u1r, rot1)
    if (has3) BSMROW(xr2, br2, u2r, rot2)
#undef BSMROW
    WAVESYNC();  // c (own wave) visible to cx (own wave)

    // (c) cx for this wave's u's: roles l < 10*nu: o = l/nu (slow), j = l%nu.
    // s_c reads: bank = (o + (s+u)) mod 32 across lanes -> spread.
    if (l < kO * nu) {
      const int o = l / nu;
      const int j = l - o * nu;
      const int u = UOFJ(j);
      float4 p0 = make_float4(0.f, 0.f, 0.f, 0.f);
      float4 p1 = make_float4(0.f, 0.f, 0.f, 0.f);
      const float* cbase = &s_c[o * kCP + u * 32];
      const float* xbase = &s_x[u * 256];
#pragma unroll 8
      for (int s = 0; s < kS; ++s) {
        const int rot = (s + u) & 31;
        const int sl0 = ((s << 1) + u) & 63;
        const int sl1 = ((s << 1) + 1 + u) & 63;
        const float4 xa = *reinterpret_cast<const float4*>(&xbase[sl0 * 4]);
        const float4 xb = *reinterpret_cast<const float4*>(&xbase[sl1 * 4]);
        const float c0 = cbase[rot];
        p0.x += c0 * xa.x; p0.y += c0 * xa.y; p0.z += c0 * xa.z; p0.w += c0 * xa.w;
        p1.x += c0 * xb.x; p1.y += c0 * xb.y; p1.z += c0 * xb.z; p1.w += c0 * xb.w;
      }
      float4* d = reinterpret_cast<float4*>(&s_cx[(o * kU + u) * kPitch]);
      d[0] = p0;
      d[1] = p1;
    }
    __syncthreads();  // s_cx visible to next v_pre (block-wide)
  }
#undef UOFJ
}

}  // namespace

extern "C" void kernel_launch(void* const* d_in, const int* in_sizes, int n_in,
                              void* d_out, int out_size, void* d_ws, size_t ws_size,
                              hipStream_t stream) {
  const float* x = (const float*)d_in[0];  // (B, 1152, 8) fp32
  const float* W = (const float*)d_in[1];  // (10, 36, 16, 8) fp32
  float* out = (float*)d_out;              // (B, 10, 16) fp32

  const int batch = in_sizes[0] / (kN * kF);  // 256
  caps_routing_kernel<<<dim3(batch), dim3(kThreads), 0, stream>>>(x, W, out);
}